// Round 1
// baseline (4996.376 us; speedup 1.0000x reference)
//
#include <hip/hip_runtime.h>
#include <math.h>

#define BB   512
#define TT   256
#define HH   512
#define DIN  514
#define DOUTN 2
#define DT   0.1f

__device__ __forceinline__ float retanh_f(float a) {
    float t = tanhf(a);
    return t > 0.0f ? t : 0.0f;
}

// ---------------------------------------------------------------------------
// Kernel 1: transpose W_x_ah [H,DIN] -> WxT [DIN,H] and W_h_ah [H,H] -> WhT [H,H]
// One-time, tiny. Coalesced writes, scattered reads.
// ---------------------------------------------------------------------------
__global__ void transpose_w(const float* __restrict__ Wx, const float* __restrict__ Wh,
                            float* __restrict__ WxT, float* __restrict__ WhT) {
    int idx = blockIdx.x * 256 + threadIdx.x;
    if (idx < DIN * HH) {
        int d = idx / HH, j = idx % HH;
        WxT[idx] = Wx[j * DIN + d];
    } else {
        int idx2 = idx - DIN * HH;
        if (idx2 < HH * HH) {
            int k = idx2 / HH, j = idx2 % HH;
            WhT[idx2] = Wh[j * HH + k];
        }
    }
}

// ---------------------------------------------------------------------------
// Kernel 2: x2ah[i,j] = sum_d x[i,d] * WxT[d,j] + b[j]   (i over B*T rows)
// Written into the hstore region of d_out (consumed then overwritten by scan).
// Block 256 threads; each thread owns 2 output columns (j=2*tid, 2*tid+1);
// 16 rows staged in LDS per workgroup. fp32 FMA, compute-bound.
// ---------------------------------------------------------------------------
__global__ __launch_bounds__(256) void x2ah_kernel(const float* __restrict__ X,
                                                   const float* __restrict__ WxT,
                                                   const float* __restrict__ bias,
                                                   float* __restrict__ outr) {
    __shared__ float xs[16][516];  // padded row (516*4=2064B, 16B aligned per row)
    const int tid = threadIdx.x;
    const int r0  = blockIdx.x * 16;

    #pragma unroll
    for (int m = 0; m < 16; ++m) {
        const float* xr = X + (r0 + m) * DIN;
        xs[m][tid]       = xr[tid];
        xs[m][tid + 256] = xr[tid + 256];
        if (tid < 2) xs[m][512 + tid] = xr[512 + tid];
    }
    __syncthreads();

    const int j = 2 * tid;
    const float2 bv = *(const float2*)&bias[j];
    float acc[16][2];
    #pragma unroll
    for (int m = 0; m < 16; ++m) { acc[m][0] = bv.x; acc[m][1] = bv.y; }

    for (int d = 0; d < 512; d += 4) {
        const float2 w0 = *(const float2*)&WxT[(d + 0) * HH + j];
        const float2 w1 = *(const float2*)&WxT[(d + 1) * HH + j];
        const float2 w2 = *(const float2*)&WxT[(d + 2) * HH + j];
        const float2 w3 = *(const float2*)&WxT[(d + 3) * HH + j];
        #pragma unroll
        for (int m = 0; m < 16; ++m) {
            const float4 xv = *(const float4*)&xs[m][d];
            acc[m][0] += xv.x * w0.x; acc[m][1] += xv.x * w0.y;
            acc[m][0] += xv.y * w1.x; acc[m][1] += xv.y * w1.y;
            acc[m][0] += xv.z * w2.x; acc[m][1] += xv.z * w2.y;
            acc[m][0] += xv.w * w3.x; acc[m][1] += xv.w * w3.y;
        }
    }
    // tail d = 512, 513
    {
        const float2 wa = *(const float2*)&WxT[512 * HH + j];
        const float2 wb = *(const float2*)&WxT[513 * HH + j];
        #pragma unroll
        for (int m = 0; m < 16; ++m) {
            acc[m][0] += xs[m][512] * wa.x; acc[m][1] += xs[m][512] * wa.y;
            acc[m][0] += xs[m][513] * wb.x; acc[m][1] += xs[m][513] * wb.y;
        }
    }
    #pragma unroll
    for (int m = 0; m < 16; ++m) {
        *(float2*)&outr[(r0 + m) * HH + j] = make_float2(acc[m][0], acc[m][1]);
    }
}

// ---------------------------------------------------------------------------
// Kernel 3: the sequential scan. One WG per 4 batches; loops all 256 steps.
// h state in LDS (broadcast reads), ah state in registers.
// Reads x2ah from the hstore region and overwrites it with h (same thread,
// same step -> trivially ordered).
// ---------------------------------------------------------------------------
__global__ __launch_bounds__(256) void scan_kernel(const float* __restrict__ WhT,
                                                   const float* __restrict__ noise,
                                                   const float* __restrict__ ah0,
                                                   float* __restrict__ hstore) {
    __shared__ float hs[4][512];
    const int tid = threadIdx.x;
    const int j   = 2 * tid;
    const int b0  = blockIdx.x * 4;

    float ahv[4][2];
    const float2 a0 = *(const float2*)&ah0[j];
    #pragma unroll
    for (int m = 0; m < 4; ++m) {
        ahv[m][0] = a0.x; ahv[m][1] = a0.y;
        hs[m][j]     = retanh_f(a0.x);
        hs[m][j + 1] = retanh_f(a0.y);
    }
    __syncthreads();

    for (int t = 0; t < TT; ++t) {
        // prefetch this step's input drive + noise (independent of hs)
        float2 xa[4], nz[4];
        #pragma unroll
        for (int m = 0; m < 4; ++m) {
            const int idx = ((b0 + m) * TT + t) * HH + j;
            xa[m] = *(const float2*)&hstore[idx];
            nz[m] = *(const float2*)&noise[idx];
        }

        float s[4][2];
        #pragma unroll
        for (int m = 0; m < 4; ++m) { s[m][0] = 0.0f; s[m][1] = 0.0f; }

        #pragma unroll 4
        for (int k = 0; k < HH; k += 4) {
            const float2 w0 = *(const float2*)&WhT[(k + 0) * HH + j];
            const float2 w1 = *(const float2*)&WhT[(k + 1) * HH + j];
            const float2 w2 = *(const float2*)&WhT[(k + 2) * HH + j];
            const float2 w3 = *(const float2*)&WhT[(k + 3) * HH + j];
            #pragma unroll
            for (int m = 0; m < 4; ++m) {
                const float4 hv = *(const float4*)&hs[m][k];
                s[m][0] += hv.x * w0.x; s[m][1] += hv.x * w0.y;
                s[m][0] += hv.y * w1.x; s[m][1] += hv.y * w1.y;
                s[m][0] += hv.z * w2.x; s[m][1] += hv.z * w2.y;
                s[m][0] += hv.w * w3.x; s[m][1] += hv.w * w3.y;
            }
        }
        __syncthreads();  // all reads of hs done before overwrite

        #pragma unroll
        for (int m = 0; m < 4; ++m) {
            ahv[m][0] += DT * (s[m][0] + xa[m].x - ahv[m][0]);
            ahv[m][1] += DT * (s[m][1] + xa[m].y - ahv[m][1]);
            const float h0 = retanh_f(ahv[m][0]) + nz[m].x;
            const float h1 = retanh_f(ahv[m][1]) + nz[m].y;
            const int idx = ((b0 + m) * TT + t) * HH + j;
            *(float2*)&hstore[idx] = make_float2(h0, h1);
            hs[m][j]     = h0;
            hs[m][j + 1] = h1;
        }
        __syncthreads();  // hs updated before next step's GEMM
    }
}

// ---------------------------------------------------------------------------
// Kernel 4: output[b,t,o] = sum_j hstore[b,t,j] * W_h_y[o,j]. Memory-bound.
// One wave per row; float4 loads; wave shuffle reduction.
// ---------------------------------------------------------------------------
__global__ __launch_bounds__(256) void out_kernel(const float* __restrict__ hstore,
                                                  const float* __restrict__ Wy,
                                                  float* __restrict__ out0) {
    const int wave = threadIdx.x >> 6;
    const int lane = threadIdx.x & 63;
    const int r = blockIdx.x * 4 + wave;

    const float4* hv4 = (const float4*)&hstore[r * HH];
    float a0 = 0.0f, a1 = 0.0f;
    #pragma unroll
    for (int u = 0; u < 2; ++u) {
        const int e = u * 64 + lane;          // float4 index within the 512-row
        const float4 h  = hv4[e];
        const float4 w0 = *(const float4*)&Wy[e * 4];
        const float4 w1 = *(const float4*)&Wy[HH + e * 4];
        a0 += h.x * w0.x + h.y * w0.y + h.z * w0.z + h.w * w0.w;
        a1 += h.x * w1.x + h.y * w1.y + h.z * w1.z + h.w * w1.w;
    }
    #pragma unroll
    for (int off = 32; off > 0; off >>= 1) {
        a0 += __shfl_xor(a0, off);
        a1 += __shfl_xor(a1, off);
    }
    if (lane == 0) {
        out0[r * 2]     = a0;
        out0[r * 2 + 1] = a1;
    }
}

// ---------------------------------------------------------------------------
extern "C" void kernel_launch(void* const* d_in, const int* in_sizes, int n_in,
                              void* d_out, int out_size, void* d_ws, size_t ws_size,
                              hipStream_t stream) {
    const float* x     = (const float*)d_in[0];  // [B,T,DIN]
    const float* noise = (const float*)d_in[1];  // [B,T,H]
    const float* Wx    = (const float*)d_in[2];  // [H,DIN]
    const float* bah   = (const float*)d_in[3];  // [H]
    const float* Wh    = (const float*)d_in[4];  // [H,H]
    const float* Wy    = (const float*)d_in[5];  // [DOUT,H]
    const float* ah0   = (const float*)d_in[6];  // [H]

    float* out0   = (float*)d_out;                 // [B,T,DOUT]
    float* hstore = (float*)d_out + BB * TT * DOUTN; // [B,T,H]

    float* WxT = (float*)d_ws;             // [DIN,H]  1.05 MB
    float* WhT = WxT + DIN * HH;           // [H,H]    1.0 MB

    transpose_w<<<(DIN * HH + HH * HH + 255) / 256, 256, 0, stream>>>(Wx, Wh, WxT, WhT);
    x2ah_kernel<<<BB * TT / 16, 256, 0, stream>>>(x, WxT, bah, hstore);
    scan_kernel<<<BB / 4, 256, 0, stream>>>(WhT, noise, ah0, hstore);
    out_kernel<<<BB * TT / 4, 256, 0, stream>>>(hstore, Wy, out0);
}